// Round 13
// baseline (37.139 us; speedup 1.0000x reference)
//
#include <hip/hip_runtime.h>

typedef float f32x4 __attribute__((ext_vector_type(4)));
typedef short bf16x8 __attribute__((ext_vector_type(8)));
typedef __bf16 bf16x2_t __attribute__((ext_vector_type(2)));
typedef unsigned int u32;
typedef unsigned long long u64;

__device__ __forceinline__ u32 pk2(float a, float b){
  bf16x2_t h; h[0] = (__bf16)a; h[1] = (__bf16)b;
  return __builtin_bit_cast(u32, h);
}
__device__ __forceinline__ unsigned short f2bf(float f){
  __bf16 h = (__bf16)f;
  return __builtin_bit_cast(unsigned short, h);
}
__device__ __forceinline__ float bf2f(unsigned short h){
  u32 u = ((u32)h) << 16;
  return __builtin_bit_cast(float, u);
}

// ws layout in ushort units — ALL tensors fragment-packed: frag[idx][lane][8].
#define WS_WOF   98304u    // Wo_foldT frags
#define WS_QF    131072u   // q frags
#define WS_KF    655360u   // k frags per batch
#define WS_VF    1179648u  // vT frags per batch
// float-indexed partial buffers (offsets in floats within ws):
#define WS_PNUM  851968u   // [batch][q32 0..63][kvhalf][32][64] fp32
#define WS_PDEN  1900544u  // [batch][q32][kvhalf][32] fp32

#define QSCALE 0.18033688011112042f   // 0.125 * log2(e)
#define PSTR 72

// B-fragment gather straight from fp32 W (row-major [512][64], L1/L2-resident)
__device__ __forceinline__ bf16x8 wfrag(const float* __restrict__ W, int kc, int cg,
                                        int g, int ln){
  const float* p = W + (size_t)(kc*32 + g*8)*64 + cg*16 + ln;
  union { bf16x8 v8; u32 w[4]; } u;
  #pragma unroll
  for (int j = 0; j < 4; ++j)
    u.w[j] = pk2(p[(2*j)*64], p[(2*j+1)*64]);
  return u.v8;
}

// ---------------- K1: projection GEMMs + Wo fold (grid 256 x 4, 128 thr) ----
__global__ __launch_bounds__(128) void k_proj(const float* __restrict__ q,
    const float* __restrict__ kmat, const float* __restrict__ v,
    const float* __restrict__ bq, const float* __restrict__ bk,
    const float* __restrict__ bv, const float* __restrict__ Wq,
    const float* __restrict__ Wk, const float* __restrict__ Wv,
    const float* __restrict__ Wo, unsigned short* __restrict__ wsu){
  const int which = blockIdx.y;
  const int t = threadIdx.x;
  if (which == 3){
    int id = blockIdx.x*128 + t;              // exactly 32768
    int j = id & 7, lf = (id >> 3) & 63, kt = (id >> 9) & 1, c16 = id >> 10;
    int n = c16*16 + (lf & 15), k = kt*32 + (lf >> 4)*8 + j;
    float s = 0.f;
    #pragma unroll
    for (int h = 0; h < 8; ++h) s += Wo[(h*64 + k)*512 + n];
    wsu[WS_WOF + id] = f2bf(s);
    return;
  }

  __shared__ unsigned short Xs[2][2048];
  const float* X    = which==0 ? q  : (which==1 ? kmat : v);
  const float* bias = which==0 ? bq : (which==1 ? bk   : bv);
  const float* W    = which==0 ? Wq : (which==1 ? Wk   : Wv);
  const int rowbase = blockIdx.x * 32;
  const int w = t >> 6, l = t & 63, g = l >> 4, ln = l & 15;

  f32x4 acc[2][2];
  #pragma unroll
  for (int rt = 0; rt < 2; ++rt)
    #pragma unroll
    for (int ntl = 0; ntl < 2; ++ntl) acc[rt][ntl] = (f32x4){0.f,0.f,0.f,0.f};
  float bcol[2];
  #pragma unroll
  for (int ntl = 0; ntl < 2; ++ntl) bcol[ntl] = bias[(w*2+ntl)*16 + ln];

  f32x4 xr[4];
  bf16x8 bc[2][2], bn[2][2];

  #pragma unroll
  for (int j = 0; j < 4; ++j){
    int c = t + j*128; int row = c >> 4, kc = c & 15;
    xr[j] = __builtin_nontemporal_load(reinterpret_cast<const f32x4*>(X + (rowbase+row)*512 + kc*4));
  }
  #pragma unroll
  for (int ntl = 0; ntl < 2; ++ntl)
    #pragma unroll
    for (int kt = 0; kt < 2; ++kt)
      bc[ntl][kt] = wfrag(W, 0*2+kt, w*2+ntl, g, ln);

  #pragma unroll
  for (int i = 0; i < 8; ++i){
    char* Xc = reinterpret_cast<char*>(Xs[i & 1]);
    #pragma unroll
    for (int j = 0; j < 4; ++j){
      int c = t + j*128; int row = c >> 4, kc = c & 15;
      u64 pk = (u64)pk2(xr[j][0], xr[j][1]) | ((u64)pk2(xr[j][2], xr[j][3]) << 32);
      *reinterpret_cast<u64*>(Xc + row*128 + ((kc*8) ^ ((row&7)<<4))) = pk;
    }
    if (i < 7){
      #pragma unroll
      for (int j = 0; j < 4; ++j){
        int c = t + j*128; int row = c >> 4, kc = c & 15;
        xr[j] = __builtin_nontemporal_load(reinterpret_cast<const f32x4*>(X + (rowbase+row)*512 + (i+1)*64 + kc*4));
      }
    }
    __syncthreads();
    if (i < 7){
      #pragma unroll
      for (int ntl = 0; ntl < 2; ++ntl)
        #pragma unroll
        for (int kt = 0; kt < 2; ++kt)
          bn[ntl][kt] = wfrag(W, (i+1)*2+kt, w*2+ntl, g, ln);
    }
    bf16x8 a[2][2];
    #pragma unroll
    for (int rt = 0; rt < 2; ++rt){
      int arow = rt*16 + ln;
      #pragma unroll
      for (int kt = 0; kt < 2; ++kt)
        a[rt][kt] = *reinterpret_cast<const bf16x8*>(Xc + arow*128 + ((kt*64 + g*16) ^ ((arow&7)<<4)));
    }
    #pragma unroll
    for (int ntl = 0; ntl < 2; ++ntl)
      #pragma unroll
      for (int kt = 0; kt < 2; ++kt)
        #pragma unroll
        for (int rt = 0; rt < 2; ++rt)
          acc[rt][ntl] = __builtin_amdgcn_mfma_f32_16x16x32_bf16(a[rt][kt], bc[ntl][kt], acc[rt][ntl], 0, 0, 0);
    if (i < 7){
      #pragma unroll
      for (int ntl = 0; ntl < 2; ++ntl)
        #pragma unroll
        for (int kt = 0; kt < 2; ++kt)
          bc[ntl][kt] = bn[ntl][kt];
    }
  }

  char* Xb = reinterpret_cast<char*>(Xs[0]);
  __syncthreads();
  if (which < 2){
    const float sc = (which==0) ? QSCALE : 1.0f;
    #pragma unroll
    for (int rt = 0; rt < 2; ++rt)
      #pragma unroll
      for (int ntl = 0; ntl < 2; ++ntl)
        #pragma unroll
        for (int r = 0; r < 4; ++r){
          int row = rt*16 + g*4 + r, col = (w*2+ntl)*16 + ln;
          *reinterpret_cast<unsigned short*>(Xb + row*128 + ((col*2) ^ ((row&7)<<4))) =
              f2bf((acc[rt][ntl][r] + bcol[ntl]) * sc);
        }
    __syncthreads();
    unsigned short* base = (which==0)
        ? wsu + WS_QF + (unsigned)(((rowbase>>4) + w)*2)*512u
        : wsu + WS_KF + (unsigned)(rowbase>>11)*131072u + (unsigned)((((rowbase&2047)>>4) + w)*2)*512u;
    const int arow = w*16 + ln;
    #pragma unroll
    for (int kt = 0; kt < 2; ++kt){
      bf16x8 f = *reinterpret_cast<const bf16x8*>(Xb + arow*128 + ((kt*64 + g*16) ^ ((arow&7)<<4)));
      *reinterpret_cast<bf16x8*>(base + kt*512 + l*8) = f;
    }
  } else {
    #pragma unroll
    for (int rt = 0; rt < 2; ++rt)
      #pragma unroll
      for (int ntl = 0; ntl < 2; ++ntl)
        #pragma unroll
        for (int r = 0; r < 4; ++r){
          int kv = rt*16 + g*4 + r, d = (w*2+ntl)*16 + ln;
          *reinterpret_cast<unsigned short*>(Xb + d*64 + ((kv*2) ^ ((d&3)<<4))) =
              f2bf(acc[rt][ntl][r] + bcol[ntl]);
        }
    __syncthreads();
    unsigned short* vfb = wsu + WS_VF + (unsigned)(rowbase>>11)*131072u;
    const int kv32 = (rowbase & 2047) >> 5;
    #pragma unroll
    for (int dtl = 0; dtl < 2; ++dtl){
      int dt = w*2 + dtl;
      int rd = dt*16 + ln;
      bf16x8 f = *reinterpret_cast<const bf16x8*>(Xb + rd*64 + ((g*16) ^ ((rd&3)<<4)));
      *reinterpret_cast<bf16x8*>(vfb + (unsigned)((kv32*4 + dt)*64 + l)*8u) = f;
    }
  }
}

// ---------------- K2: flash attention partials (QBLK=64, 2-way kv-split) ----
// grid 256: xcd=bid&7 -> batch=xcd>>1, kvhalf=xcd&1; qtile64 = bid>>3.
// 8 waves: qg = w>>2 (32-row half of the 64-row tile), kvs = w&3 (256-kv slice
// of this block's 1024-kv half). Inner loop identical to R12.
__global__ __launch_bounds__(512) void k_attn(unsigned short* __restrict__ wsu){
  __shared__ __attribute__((aligned(16))) unsigned char smem[37888];
  // [0,36864): per-wave po/P regions (w*4608); [36864,37888): pls float[8][32]

  const int t = threadIdx.x;
  const int w = t >> 6, l = t & 63, g = l >> 4, ln = l & 15;
  const int bid = blockIdx.x;
  const int xcd = bid & 7;
  const int batch = xcd >> 1;
  const int kvhalf = xcd & 1;
  const int qtile = bid >> 3;                  // 0..31 (64-row tiles)
  const int qg = w >> 2, kvs = w & 3;
  const int qbase = batch*2048 + qtile*64 + qg*32;
  const int kv0 = kvhalf*1024 + kvs*256;

  const unsigned short* qf  = wsu + WS_QF;
  const unsigned short* kfb = wsu + WS_KF + (unsigned)batch*131072u;
  const unsigned short* vfb = wsu + WS_VF + (unsigned)batch*131072u;
  float* wsf = (float*)wsu;

  unsigned short* Pw  = (unsigned short*)(smem + w*4608);
  float*          pls = (float*)(smem + 36864);

  const int q16 = qbase >> 4;
  bf16x8 qa[2][2];
  #pragma unroll
  for (int rt = 0; rt < 2; ++rt)
    #pragma unroll
    for (int kt = 0; kt < 2; ++kt)
      qa[rt][kt] = *reinterpret_cast<const bf16x8*>(qf + (unsigned)(((q16+rt)*2 + kt)*64 + l)*8u);

  f32x4 o[4][2];
  #pragma unroll
  for (int dt = 0; dt < 4; ++dt)
    #pragma unroll
    for (int rt = 0; rt < 2; ++rt) o[dt][rt] = (f32x4){0.f,0.f,0.f,0.f};
  float ls[2] = {0.f, 0.f};

  #pragma unroll
  for (int it = 0; it < 4; ++it){
    const int kvb = kv0 + it*64;
    const int kv16 = kvb >> 4, kv32 = kvb >> 5;
    bf16x8 ka[4][2];
    #pragma unroll
    for (int ct = 0; ct < 4; ++ct)
      #pragma unroll
      for (int kt = 0; kt < 2; ++kt)
        ka[ct][kt] = *reinterpret_cast<const bf16x8*>(kfb + (unsigned)(((kv16+ct)*2 + kt)*64 + l)*8u);
    f32x4 st[4][2];
    #pragma unroll
    for (int ct = 0; ct < 4; ++ct)
      #pragma unroll
      for (int rt = 0; rt < 2; ++rt){
        st[ct][rt] = (f32x4){0.f,0.f,0.f,0.f};
        #pragma unroll
        for (int kt = 0; kt < 2; ++kt)
          st[ct][rt] = __builtin_amdgcn_mfma_f32_16x16x32_bf16(ka[ct][kt], qa[rt][kt], st[ct][rt], 0,0,0);
      }
    bf16x8 vb[4][2];
    #pragma unroll
    for (int dt = 0; dt < 4; ++dt)
      #pragma unroll
      for (int kvt = 0; kvt < 2; ++kvt)
        vb[dt][kvt] = *reinterpret_cast<const bf16x8*>(vfb + (unsigned)(((kv32+kvt)*4 + dt)*64 + l)*8u);

    #pragma unroll
    for (int rt = 0; rt < 2; ++rt){
      float p[4][4];
      float rs = 0.f;
      #pragma unroll
      for (int ct = 0; ct < 4; ++ct)
        #pragma unroll
        for (int r = 0; r < 4; ++r){
          p[ct][r] = exp2f(st[ct][rt][r]);
          rs += p[ct][r];
        }
      rs += __shfl_xor(rs, 16, 64);
      rs += __shfl_xor(rs, 32, 64);
      ls[rt] += rs;
      unsigned short* pr = Pw + (rt*16 + ln)*PSTR;
      #pragma unroll
      for (int ct = 0; ct < 4; ++ct){
        *reinterpret_cast<u32*>(pr + ct*16 + g*4)     = pk2(p[ct][0], p[ct][1]);
        *reinterpret_cast<u32*>(pr + ct*16 + g*4 + 2) = pk2(p[ct][2], p[ct][3]);
      }
    }
    bf16x8 pb[2][2];
    #pragma unroll
    for (int rt = 0; rt < 2; ++rt)
      #pragma unroll
      for (int kvt = 0; kvt < 2; ++kvt)
        pb[rt][kvt] = *reinterpret_cast<const bf16x8*>(Pw + (rt*16 + ln)*PSTR + kvt*32 + g*8);
    #pragma unroll
    for (int dt = 0; dt < 4; ++dt)
      #pragma unroll
      for (int rt = 0; rt < 2; ++rt)
        #pragma unroll
        for (int kvt = 0; kvt < 2; ++kvt)
          o[dt][rt] = __builtin_amdgcn_mfma_f32_16x16x32_bf16(vb[dt][kvt], pb[rt][kvt], o[dt][rt], 0,0,0);
  }

  // per-wave partials to LDS
  if (l < 16){ pls[w*32 + ln] = ls[0]; pls[w*32 + 16 + ln] = ls[1]; }
  unsigned short* pow_ = (unsigned short*)(smem + w*4608);
  #pragma unroll
  for (int dt = 0; dt < 4; ++dt)
    #pragma unroll
    for (int rt = 0; rt < 2; ++rt){
      u32* dst = reinterpret_cast<u32*>(pow_ + (rt*16 + ln)*68 + dt*16 + g*4);
      dst[0] = pk2(o[dt][rt][0], o[dt][rt][1]);
      dst[1] = pk2(o[dt][rt][2], o[dt][rt][3]);
    }
  __syncthreads();

  // merge this block's 4 waves per q-group -> fp32 partial num/den to ws
  const unsigned pb0 = (unsigned)(batch*64 + qtile*2);
  #pragma unroll
  for (int i = 0; i < 8; ++i){
    int idx = t + i*512;                       // 0..4095
    int qg2 = idx >> 11, row = (idx >> 6) & 31, d = idx & 63;
    float num = 0.f;
    #pragma unroll
    for (int j = 0; j < 4; ++j)
      num += bf2f(*((const unsigned short*)(smem + (qg2*4 + j)*4608) + row*68 + d));
    wsf[WS_PNUM + (unsigned)(((pb0 + qg2)*2 + kvhalf))*2048u + row*64 + d] = num;
    if (d == 0){
      float den = 0.f;
      #pragma unroll
      for (int j = 0; j < 4; ++j) den += pls[(qg2*4 + j)*32 + row];
      wsf[WS_PDEN + (unsigned)(((pb0 + qg2)*2 + kvhalf))*32u + row] = den;
    }
  }
}

// ---------------- K3: merge kv-halves + output projection -------------------
// grid (64,4): q32 tile x batch. 512 thr, 8 waves (wave = 64-col group).
__global__ __launch_bounds__(512) void k_merge(const unsigned short* __restrict__ wsu,
    const float* __restrict__ bo, float* __restrict__ out){
  __shared__ __attribute__((aligned(16))) unsigned short ob[32*PSTR];

  const int t = threadIdx.x;
  const int w = t >> 6, l = t & 63, g = l >> 4, ln = l & 15;
  const int q32 = blockIdx.x, batch = blockIdx.y;
  const int qbase = batch*2048 + q32*32;
  const float* wsf = (const float*)wsu;
  const unsigned short* wof = wsu + WS_WOF;

  {
    const int row = t >> 4, ds = (t & 15)*4;
    const unsigned pi = (unsigned)((batch*64 + q32)*2);
    f32x4 n0 = *reinterpret_cast<const f32x4*>(&wsf[WS_PNUM + pi*2048u + row*64 + ds]);
    f32x4 n1 = *reinterpret_cast<const f32x4*>(&wsf[WS_PNUM + (pi+1)*2048u + row*64 + ds]);
    float den = wsf[WS_PDEN + pi*32u + row] + wsf[WS_PDEN + (pi+1)*32u + row];
    float rin = 1.0f / den;
    u32* dst = reinterpret_cast<u32*>(&ob[row*PSTR + ds]);
    dst[0] = pk2((n0[0]+n1[0])*rin, (n0[1]+n1[1])*rin);
    dst[1] = pk2((n0[2]+n1[2])*rin, (n0[3]+n1[3])*rin);
  }
  __syncthreads();

  const int colbase = w*64;
  bf16x8 ao[2][2];
  #pragma unroll
  for (int rt = 0; rt < 2; ++rt)
    #pragma unroll
    for (int kt = 0; kt < 2; ++kt)
      ao[rt][kt] = *reinterpret_cast<const bf16x8*>(ob + (rt*16 + ln)*PSTR + kt*32 + g*8);
  f32x4 oc[2][4];
  #pragma unroll
  for (int rt = 0; rt < 2; ++rt)
    #pragma unroll
    for (int nt = 0; nt < 4; ++nt) oc[rt][nt] = (f32x4){0.f,0.f,0.f,0.f};
  #pragma unroll
  for (int nt = 0; nt < 4; ++nt){
    #pragma unroll
    for (int kt = 0; kt < 2; ++kt){
      bf16x8 b = *reinterpret_cast<const bf16x8*>(wof + (unsigned)(((w*4+nt)*2 + kt)*64 + l)*8u);
      #pragma unroll
      for (int rt = 0; rt < 2; ++rt)
        oc[rt][nt] = __builtin_amdgcn_mfma_f32_16x16x32_bf16(ao[rt][kt], b, oc[rt][nt], 0,0,0);
    }
  }
  #pragma unroll
  for (int nt = 0; nt < 4; ++nt){
    float bc = bo[colbase + nt*16 + ln];
    #pragma unroll
    for (int rt = 0; rt < 2; ++rt){
      #pragma unroll
      for (int r = 0; r < 4; ++r){
        int row = qbase + rt*16 + g*4 + r;
        __builtin_nontemporal_store(oc[rt][nt][r] + bc, &out[row*512 + colbase + nt*16 + ln]);
      }
    }
  }
}

extern "C" void kernel_launch(void* const* d_in, const int* in_sizes, int n_in,
                              void* d_out, int out_size, void* d_ws, size_t ws_size,
                              hipStream_t stream){
  const float* q  = (const float*)d_in[0];
  const float* k  = (const float*)d_in[1];
  const float* v  = (const float*)d_in[2];
  const float* Wq = (const float*)d_in[3];
  const float* bq = (const float*)d_in[4];
  const float* Wk = (const float*)d_in[5];
  const float* bk = (const float*)d_in[6];
  const float* Wv = (const float*)d_in[7];
  const float* bv = (const float*)d_in[8];
  const float* Wo = (const float*)d_in[9];
  const float* bo = (const float*)d_in[10];
  float* out = (float*)d_out;
  unsigned short* wsu = (unsigned short*)d_ws;

  k_proj<<<dim3(256, 4), dim3(128), 0, stream>>>(q, k, v, bq, bk, bv, Wq, Wk, Wv, Wo, wsu);
  k_attn<<<dim3(256), dim3(512), 0, stream>>>(wsu);
  k_merge<<<dim3(64, 4), dim3(512), 0, stream>>>(wsu, bo, out);
}

// Round 14
// 35.574 us; speedup vs baseline: 1.0440x; 1.0440x over previous
//
#include <hip/hip_runtime.h>

typedef float f32x4 __attribute__((ext_vector_type(4)));
typedef short bf16x8 __attribute__((ext_vector_type(8)));
typedef __bf16 bf16x2_t __attribute__((ext_vector_type(2)));
typedef unsigned int u32;
typedef unsigned long long u64;

__device__ __forceinline__ u32 pk2(float a, float b){
  bf16x2_t h; h[0] = (__bf16)a; h[1] = (__bf16)b;
  return __builtin_bit_cast(u32, h);
}
__device__ __forceinline__ unsigned short f2bf(float f){
  __bf16 h = (__bf16)f;
  return __builtin_bit_cast(unsigned short, h);
}
__device__ __forceinline__ float bf2f(unsigned short h){
  u32 u = ((u32)h) << 16;
  return __builtin_bit_cast(float, u);
}

// ws layout in ushort units — ALL tensors fragment-packed: frag[idx][lane][8].
#define WS_WOF   98304u    // Wo_foldT frags: ((c16*2+kt)*64+l)*8+j   (c16 0..31)
#define WS_QF    131072u   // q frags:  ((q16*2+kt)*64+l)*8+j         (q16 0..511)
#define WS_KF    655360u   // k frags:  batch*131072 + ((kv16*2+kt)*64+l)*8+j
#define WS_VF    1179648u  // vT frags: batch*131072 + ((kv32*4+dt)*64+l)*8+j

#define QSCALE 0.18033688011112042f   // 0.125 * log2(e)

// B-fragment gather straight from fp32 W (row-major [512][64], L1/L2-resident)
__device__ __forceinline__ bf16x8 wfrag(const float* __restrict__ W, int kc, int cg,
                                        int g, int ln){
  const float* p = W + (size_t)(kc*32 + g*8)*64 + cg*16 + ln;
  union { bf16x8 v8; u32 w[4]; } u;
  #pragma unroll
  for (int j = 0; j < 4; ++j)
    u.w[j] = pk2(p[(2*j)*64], p[(2*j+1)*64]);
  return u.v8;
}

// ---------------- K1: projection GEMMs + Wo fold (grid 256 x 4, 128 thr) ----
__global__ __launch_bounds__(128) void k_proj(const float* __restrict__ q,
    const float* __restrict__ kmat, const float* __restrict__ v,
    const float* __restrict__ bq, const float* __restrict__ bk,
    const float* __restrict__ bv, const float* __restrict__ Wq,
    const float* __restrict__ Wk, const float* __restrict__ Wv,
    const float* __restrict__ Wo, unsigned short* __restrict__ wsu){
  const int which = blockIdx.y;
  const int t = threadIdx.x;
  if (which == 3){
    // Wo fold, written directly in fragment order (coalesced store)
    int id = blockIdx.x*128 + t;              // exactly 32768
    int j = id & 7, lf = (id >> 3) & 63, kt = (id >> 9) & 1, c16 = id >> 10;
    int n = c16*16 + (lf & 15), k = kt*32 + (lf >> 4)*8 + j;
    float s = 0.f;
    #pragma unroll
    for (int h = 0; h < 8; ++h) s += Wo[(h*64 + k)*512 + n];
    wsu[WS_WOF + id] = f2bf(s);
    return;
  }

  __shared__ unsigned short Xs[2][2048];      // dbuf staging; Xs[0] reused by epilogue
  const float* X    = which==0 ? q  : (which==1 ? kmat : v);
  const float* bias = which==0 ? bq : (which==1 ? bk   : bv);
  const float* W    = which==0 ? Wq : (which==1 ? Wk   : Wv);
  const int rowbase = blockIdx.x * 32;
  const int w = t >> 6, l = t & 63, g = l >> 4, ln = l & 15;

  f32x4 acc[2][2];                            // [rt][ntl]
  #pragma unroll
  for (int rt = 0; rt < 2; ++rt)
    #pragma unroll
    for (int ntl = 0; ntl < 2; ++ntl) acc[rt][ntl] = (f32x4){0.f,0.f,0.f,0.f};
  float bcol[2];
  #pragma unroll
  for (int ntl = 0; ntl < 2; ++ntl) bcol[ntl] = bias[(w*2+ntl)*16 + ln];

  f32x4 xr[4];
  bf16x8 bc[2][2], bn[2][2];

  #pragma unroll
  for (int j = 0; j < 4; ++j){
    int c = t + j*128; int row = c >> 4, kc = c & 15;
    xr[j] = __builtin_nontemporal_load(reinterpret_cast<const f32x4*>(X + (rowbase+row)*512 + kc*4));
  }
  #pragma unroll
  for (int ntl = 0; ntl < 2; ++ntl)
    #pragma unroll
    for (int kt = 0; kt < 2; ++kt)
      bc[ntl][kt] = wfrag(W, 0*2+kt, w*2+ntl, g, ln);

  #pragma unroll
  for (int i = 0; i < 8; ++i){
    char* Xc = reinterpret_cast<char*>(Xs[i & 1]);
    #pragma unroll
    for (int j = 0; j < 4; ++j){
      int c = t + j*128; int row = c >> 4, kc = c & 15;
      u64 pk = (u64)pk2(xr[j][0], xr[j][1]) | ((u64)pk2(xr[j][2], xr[j][3]) << 32);
      *reinterpret_cast<u64*>(Xc + row*128 + ((kc*8) ^ ((row&7)<<4))) = pk;
    }
    if (i < 7){
      #pragma unroll
      for (int j = 0; j < 4; ++j){
        int c = t + j*128; int row = c >> 4, kc = c & 15;
        xr[j] = __builtin_nontemporal_load(reinterpret_cast<const f32x4*>(X + (rowbase+row)*512 + (i+1)*64 + kc*4));
      }
    }
    __syncthreads();
    if (i < 7){
      #pragma unroll
      for (int ntl = 0; ntl < 2; ++ntl)
        #pragma unroll
        for (int kt = 0; kt < 2; ++kt)
          bn[ntl][kt] = wfrag(W, (i+1)*2+kt, w*2+ntl, g, ln);
    }
    bf16x8 a[2][2];
    #pragma unroll
    for (int rt = 0; rt < 2; ++rt){
      int arow = rt*16 + ln;
      #pragma unroll
      for (int kt = 0; kt < 2; ++kt)
        a[rt][kt] = *reinterpret_cast<const bf16x8*>(Xc + arow*128 + ((kt*64 + g*16) ^ ((arow&7)<<4)));
    }
    #pragma unroll
    for (int ntl = 0; ntl < 2; ++ntl)
      #pragma unroll
      for (int kt = 0; kt < 2; ++kt)
        #pragma unroll
        for (int rt = 0; rt < 2; ++rt)
          acc[rt][ntl] = __builtin_amdgcn_mfma_f32_16x16x32_bf16(a[rt][kt], bc[ntl][kt], acc[rt][ntl], 0, 0, 0);
    if (i < 7){
      #pragma unroll
      for (int ntl = 0; ntl < 2; ++ntl)
        #pragma unroll
        for (int kt = 0; kt < 2; ++kt)
          bc[ntl][kt] = bn[ntl][kt];
    }
  }

  char* Xb = reinterpret_cast<char*>(Xs[0]);
  __syncthreads();
  if (which < 2){
    // repack acc -> swizzled 32x64 LDS tile -> fragment order -> coalesced 1KB stores
    const float sc = (which==0) ? QSCALE : 1.0f;
    #pragma unroll
    for (int rt = 0; rt < 2; ++rt)
      #pragma unroll
      for (int ntl = 0; ntl < 2; ++ntl)
        #pragma unroll
        for (int r = 0; r < 4; ++r){
          int row = rt*16 + g*4 + r, col = (w*2+ntl)*16 + ln;
          *reinterpret_cast<unsigned short*>(Xb + row*128 + ((col*2) ^ ((row&7)<<4))) =
              f2bf((acc[rt][ntl][r] + bcol[ntl]) * sc);
        }
    __syncthreads();
    unsigned short* base = (which==0)
        ? wsu + WS_QF + (unsigned)(((rowbase>>4) + w)*2)*512u
        : wsu + WS_KF + (unsigned)(rowbase>>11)*131072u + (unsigned)((((rowbase&2047)>>4) + w)*2)*512u;
    const int arow = w*16 + ln;
    #pragma unroll
    for (int kt = 0; kt < 2; ++kt){
      bf16x8 f = *reinterpret_cast<const bf16x8*>(Xb + arow*128 + ((kt*64 + g*16) ^ ((arow&7)<<4)));
      *reinterpret_cast<bf16x8*>(base + kt*512 + l*8) = f;
    }
  } else {
    // V: transposed 64x32 LDS tile (swizzled) -> V^T fragments -> coalesced stores
    #pragma unroll
    for (int rt = 0; rt < 2; ++rt)
      #pragma unroll
      for (int ntl = 0; ntl < 2; ++ntl)
        #pragma unroll
        for (int r = 0; r < 4; ++r){
          int kv = rt*16 + g*4 + r, d = (w*2+ntl)*16 + ln;
          *reinterpret_cast<unsigned short*>(Xb + d*64 + ((kv*2) ^ ((d&3)<<4))) =
              f2bf(acc[rt][ntl][r] + bcol[ntl]);
        }
    __syncthreads();
    unsigned short* vfb = wsu + WS_VF + (unsigned)(rowbase>>11)*131072u;
    const int kv32 = (rowbase & 2047) >> 5;
    #pragma unroll
    for (int dtl = 0; dtl < 2; ++dtl){
      int dt = w*2 + dtl;
      int rd = dt*16 + ln;
      bf16x8 f = *reinterpret_cast<const bf16x8*>(Xb + rd*64 + ((g*16) ^ ((rd&3)<<4)));
      *reinterpret_cast<bf16x8*>(vfb + (unsigned)((kv32*4 + dt)*64 + l)*8u) = f;
    }
  }
}

// ---------------- K2: split-KV flash attention + fused output projection ----
// R12 structure + software pipeline: V(i) and K(i+1) loads issued BEFORE the
// QK MFMAs (which consume in-register ka) — every load has softmax+PV to land.
#define PSTR 72

__global__ __launch_bounds__(512) void k_attn(const unsigned short* __restrict__ wsu,
    const float* __restrict__ bo, float* __restrict__ out){
  __shared__ __attribute__((aligned(16))) unsigned char smem[42496];

  const int t = threadIdx.x;
  const int w = t >> 6, l = t & 63, g = l >> 4, ln = l & 15;
  // XCD-aware mapping: xcd = bid%8 ; batch = xcd>>1 ; tile = (bid&1)*32 + bid>>3
  const int bid = blockIdx.x;
  const int batch = (bid & 7) >> 1;
  const int tile  = ((bid & 1) << 5) | (bid >> 3);
  const int qbase = batch*2048 + tile*32;

  const unsigned short* qf  = wsu + WS_QF;
  const unsigned short* kfb = wsu + WS_KF + (unsigned)batch*131072u;
  const unsigned short* vfb = wsu + WS_VF + (unsigned)batch*131072u;
  const unsigned short* wof = wsu + WS_WOF;

  unsigned short* Pw  = (unsigned short*)(smem + w*4608);
  float*          pls = (float*)(smem + 36864);
  unsigned short* ob  = (unsigned short*)(smem + 37888);

  const int q16 = qbase >> 4;
  bf16x8 qa[2][2];
  #pragma unroll
  for (int rt = 0; rt < 2; ++rt)
    #pragma unroll
    for (int kt = 0; kt < 2; ++kt)
      qa[rt][kt] = *reinterpret_cast<const bf16x8*>(qf + (unsigned)(((q16+rt)*2 + kt)*64 + l)*8u);

  f32x4 o[4][2];
  #pragma unroll
  for (int dt = 0; dt < 4; ++dt)
    #pragma unroll
    for (int rt = 0; rt < 2; ++rt) o[dt][rt] = (f32x4){0.f,0.f,0.f,0.f};
  float ls[2] = {0.f, 0.f};

  const int kv0 = w * 256;

  // prologue: K fragments for iter 0
  bf16x8 ka[4][2];
  {
    const int kv16 = kv0 >> 4;
    #pragma unroll
    for (int ct = 0; ct < 4; ++ct)
      #pragma unroll
      for (int kt = 0; kt < 2; ++kt)
        ka[ct][kt] = *reinterpret_cast<const bf16x8*>(kfb + (unsigned)(((kv16+ct)*2 + kt)*64 + l)*8u);
  }

  #pragma unroll
  for (int it = 0; it < 4; ++it){
    const int kvb = kv0 + it*64;
    const int kv32 = kvb >> 5;
    // issue V(i) loads first (consumed by PV, far below)
    bf16x8 vb[4][2];
    #pragma unroll
    for (int dt = 0; dt < 4; ++dt)
      #pragma unroll
      for (int kvt = 0; kvt < 2; ++kvt)
        vb[dt][kvt] = *reinterpret_cast<const bf16x8*>(vfb + (unsigned)(((kv32+kvt)*4 + dt)*64 + l)*8u);
    // issue K(i+1) loads (consumed next iteration)
    bf16x8 kan[4][2];
    if (it < 3){
      const int kv16n = (kvb + 64) >> 4;
      #pragma unroll
      for (int ct = 0; ct < 4; ++ct)
        #pragma unroll
        for (int kt = 0; kt < 2; ++kt)
          kan[ct][kt] = *reinterpret_cast<const bf16x8*>(kfb + (unsigned)(((kv16n+ct)*2 + kt)*64 + l)*8u);
    }
    // QK MFMAs consume in-register ka — no memory wait
    f32x4 st[4][2];
    #pragma unroll
    for (int ct = 0; ct < 4; ++ct)
      #pragma unroll
      for (int rt = 0; rt < 2; ++rt){
        st[ct][rt] = (f32x4){0.f,0.f,0.f,0.f};
        #pragma unroll
        for (int kt = 0; kt < 2; ++kt)
          st[ct][rt] = __builtin_amdgcn_mfma_f32_16x16x32_bf16(ka[ct][kt], qa[rt][kt], st[ct][rt], 0,0,0);
      }

    #pragma unroll
    for (int rt = 0; rt < 2; ++rt){
      float p[4][4];
      float rs = 0.f;
      #pragma unroll
      for (int ct = 0; ct < 4; ++ct)
        #pragma unroll
        for (int r = 0; r < 4; ++r){
          p[ct][r] = exp2f(st[ct][rt][r]);
          rs += p[ct][r];
        }
      rs += __shfl_xor(rs, 16, 64);
      rs += __shfl_xor(rs, 32, 64);
      ls[rt] += rs;
      unsigned short* pr = Pw + (rt*16 + ln)*PSTR;
      #pragma unroll
      for (int ct = 0; ct < 4; ++ct){
        *reinterpret_cast<u32*>(pr + ct*16 + g*4)     = pk2(p[ct][0], p[ct][1]);
        *reinterpret_cast<u32*>(pr + ct*16 + g*4 + 2) = pk2(p[ct][2], p[ct][3]);
      }
    }
    bf16x8 pb[2][2];
    #pragma unroll
    for (int rt = 0; rt < 2; ++rt)
      #pragma unroll
      for (int kvt = 0; kvt < 2; ++kvt)
        pb[rt][kvt] = *reinterpret_cast<const bf16x8*>(Pw + (rt*16 + ln)*PSTR + kvt*32 + g*8);
    #pragma unroll
    for (int dt = 0; dt < 4; ++dt)
      #pragma unroll
      for (int rt = 0; rt < 2; ++rt)
        #pragma unroll
        for (int kvt = 0; kvt < 2; ++kvt)
          o[dt][rt] = __builtin_amdgcn_mfma_f32_16x16x32_bf16(vb[dt][kvt], pb[rt][kvt], o[dt][rt], 0,0,0);
    if (it < 3){
      #pragma unroll
      for (int ct = 0; ct < 4; ++ct)
        #pragma unroll
        for (int kt = 0; kt < 2; ++kt)
          ka[ct][kt] = kan[ct][kt];
    }
  }

  if (l < 16){ pls[w*32 + ln] = ls[0]; pls[w*32 + 16 + ln] = ls[1]; }
  unsigned short* pow_ = (unsigned short*)(smem + w*4608);
  #pragma unroll
  for (int dt = 0; dt < 4; ++dt)
    #pragma unroll
    for (int rt = 0; rt < 2; ++rt){
      u32* dst = reinterpret_cast<u32*>(pow_ + (rt*16 + ln)*68 + dt*16 + g*4);
      dst[0] = pk2(o[dt][rt][0], o[dt][rt][1]);
      dst[1] = pk2(o[dt][rt][2], o[dt][rt][3]);
    }
  __syncthreads();

  #pragma unroll
  for (int i = 0; i < 4; ++i){
    int idx = t + i*512;
    int row = idx >> 6, d = idx & 63;
    float den = 0.f, num = 0.f;
    #pragma unroll
    for (int w2 = 0; w2 < 8; ++w2){
      den += pls[w2*32 + row];
      num += bf2f(*((const unsigned short*)(smem + w2*4608) + row*68 + d));
    }
    ob[row*PSTR + d] = f2bf(num / den);
  }
  __syncthreads();

  const int colbase = w*64;
  bf16x8 ao[2][2];
  #pragma unroll
  for (int rt = 0; rt < 2; ++rt)
    #pragma unroll
    for (int kt = 0; kt < 2; ++kt)
      ao[rt][kt] = *reinterpret_cast<const bf16x8*>(ob + (rt*16 + ln)*PSTR + kt*32 + g*8);
  f32x4 oc[2][4];
  #pragma unroll
  for (int rt = 0; rt < 2; ++rt)
    #pragma unroll
    for (int nt = 0; nt < 4; ++nt) oc[rt][nt] = (f32x4){0.f,0.f,0.f,0.f};
  #pragma unroll
  for (int nt = 0; nt < 4; ++nt){
    #pragma unroll
    for (int kt = 0; kt < 2; ++kt){
      bf16x8 b = *reinterpret_cast<const bf16x8*>(wof + (unsigned)(((w*4+nt)*2 + kt)*64 + l)*8u);
      #pragma unroll
      for (int rt = 0; rt < 2; ++rt)
        oc[rt][nt] = __builtin_amdgcn_mfma_f32_16x16x32_bf16(ao[rt][kt], b, oc[rt][nt], 0,0,0);
    }
  }
  #pragma unroll
  for (int nt = 0; nt < 4; ++nt){
    float bc = bo[colbase + nt*16 + ln];
    #pragma unroll
    for (int rt = 0; rt < 2; ++rt){
      #pragma unroll
      for (int r = 0; r < 4; ++r){
        int row = qbase + rt*16 + g*4 + r;
        __builtin_nontemporal_store(oc[rt][nt][r] + bc, &out[row*512 + colbase + nt*16 + ln]);
      }
    }
  }
}

extern "C" void kernel_launch(void* const* d_in, const int* in_sizes, int n_in,
                              void* d_out, int out_size, void* d_ws, size_t ws_size,
                              hipStream_t stream){
  const float* q  = (const float*)d_in[0];
  const float* k  = (const float*)d_in[1];
  const float* v  = (const float*)d_in[2];
  const float* Wq = (const float*)d_in[3];
  const float* bq = (const float*)d_in[4];
  const float* Wk = (const float*)d_in[5];
  const float* bk = (const float*)d_in[6];
  const float* Wv = (const float*)d_in[7];
  const float* bv = (const float*)d_in[8];
  const float* Wo = (const float*)d_in[9];
  const float* bo = (const float*)d_in[10];
  float* out = (float*)d_out;
  unsigned short* wsu = (unsigned short*)d_ws;

  k_proj<<<dim3(256, 4), dim3(128), 0, stream>>>(q, k, v, bq, bk, bv, Wq, Wk, Wv, Wo, wsu);
  k_attn<<<dim3(256), dim3(512), 0, stream>>>(wsu, bo, out);
}

// Round 15
// 33.063 us; speedup vs baseline: 1.1233x; 1.0759x over previous
//
#include <hip/hip_runtime.h>

typedef float f32x4 __attribute__((ext_vector_type(4)));
typedef short bf16x8 __attribute__((ext_vector_type(8)));
typedef __bf16 bf16x2_t __attribute__((ext_vector_type(2)));
typedef unsigned int u32;
typedef unsigned long long u64;

__device__ __forceinline__ u32 pk2(float a, float b){
  bf16x2_t h; h[0] = (__bf16)a; h[1] = (__bf16)b;
  return __builtin_bit_cast(u32, h);
}
__device__ __forceinline__ unsigned short f2bf(float f){
  __bf16 h = (__bf16)f;
  return __builtin_bit_cast(unsigned short, h);
}
__device__ __forceinline__ float bf2f(unsigned short h){
  u32 u = ((u32)h) << 16;
  return __builtin_bit_cast(float, u);
}

// ws layout in ushort units — ALL tensors fragment-packed: frag[idx][lane][8].
#define WS_WOF   98304u    // Wo_foldT frags: ((c16*2+kt)*64+l)*8+j   (c16 0..31)
#define WS_QF    131072u   // q frags:  ((q16*2+kt)*64+l)*8+j         (q16 0..511)
#define WS_KF    655360u   // k frags:  batch*131072 + ((kv16*2+kt)*64+l)*8+j
#define WS_VF    1179648u  // vT frags: batch*131072 + ((kv32*4+dt)*64+l)*8+j

#define QSCALE 0.18033688011112042f   // 0.125 * log2(e)

// B-fragment gather straight from fp32 W (row-major [512][64], L1/L2-resident)
__device__ __forceinline__ bf16x8 wfrag(const float* __restrict__ W, int kc, int cg,
                                        int g, int ln){
  const float* p = W + (size_t)(kc*32 + g*8)*64 + cg*16 + ln;
  union { bf16x8 v8; u32 w[4]; } u;
  #pragma unroll
  for (int j = 0; j < 4; ++j)
    u.w[j] = pk2(p[(2*j)*64], p[(2*j+1)*64]);
  return u.v8;
}

// ---------------- K1: projection GEMMs + Wo fold (grid 256 x 4, 128 thr) ----
__global__ __launch_bounds__(128) void k_proj(const float* __restrict__ q,
    const float* __restrict__ kmat, const float* __restrict__ v,
    const float* __restrict__ bq, const float* __restrict__ bk,
    const float* __restrict__ bv, const float* __restrict__ Wq,
    const float* __restrict__ Wk, const float* __restrict__ Wv,
    const float* __restrict__ Wo, unsigned short* __restrict__ wsu){
  const int which = blockIdx.y;
  const int t = threadIdx.x;
  if (which == 3){
    // Wo fold, written directly in fragment order (coalesced store)
    int id = blockIdx.x*128 + t;              // exactly 32768
    int j = id & 7, lf = (id >> 3) & 63, kt = (id >> 9) & 1, c16 = id >> 10;
    int n = c16*16 + (lf & 15), k = kt*32 + (lf >> 4)*8 + j;
    float s = 0.f;
    #pragma unroll
    for (int h = 0; h < 8; ++h) s += Wo[(h*64 + k)*512 + n];
    wsu[WS_WOF + id] = f2bf(s);
    return;
  }

  __shared__ unsigned short Xs[2][2048];      // dbuf staging; Xs[0] reused by epilogue
  const float* X    = which==0 ? q  : (which==1 ? kmat : v);
  const float* bias = which==0 ? bq : (which==1 ? bk   : bv);
  const float* W    = which==0 ? Wq : (which==1 ? Wk   : Wv);
  const int rowbase = blockIdx.x * 32;
  const int w = t >> 6, l = t & 63, g = l >> 4, ln = l & 15;

  f32x4 acc[2][2];                            // [rt][ntl]
  #pragma unroll
  for (int rt = 0; rt < 2; ++rt)
    #pragma unroll
    for (int ntl = 0; ntl < 2; ++ntl) acc[rt][ntl] = (f32x4){0.f,0.f,0.f,0.f};
  float bcol[2];
  #pragma unroll
  for (int ntl = 0; ntl < 2; ++ntl) bcol[ntl] = bias[(w*2+ntl)*16 + ln];

  f32x4 xr[4];
  bf16x8 bc[2][2], bn[2][2];

  #pragma unroll
  for (int j = 0; j < 4; ++j){
    int c = t + j*128; int row = c >> 4, kc = c & 15;
    xr[j] = __builtin_nontemporal_load(reinterpret_cast<const f32x4*>(X + (rowbase+row)*512 + kc*4));
  }
  #pragma unroll
  for (int ntl = 0; ntl < 2; ++ntl)
    #pragma unroll
    for (int kt = 0; kt < 2; ++kt)
      bc[ntl][kt] = wfrag(W, 0*2+kt, w*2+ntl, g, ln);

  #pragma unroll
  for (int i = 0; i < 8; ++i){
    char* Xc = reinterpret_cast<char*>(Xs[i & 1]);
    #pragma unroll
    for (int j = 0; j < 4; ++j){
      int c = t + j*128; int row = c >> 4, kc = c & 15;
      u64 pk = (u64)pk2(xr[j][0], xr[j][1]) | ((u64)pk2(xr[j][2], xr[j][3]) << 32);
      *reinterpret_cast<u64*>(Xc + row*128 + ((kc*8) ^ ((row&7)<<4))) = pk;
    }
    if (i < 7){
      #pragma unroll
      for (int j = 0; j < 4; ++j){
        int c = t + j*128; int row = c >> 4, kc = c & 15;
        xr[j] = __builtin_nontemporal_load(reinterpret_cast<const f32x4*>(X + (rowbase+row)*512 + (i+1)*64 + kc*4));
      }
    }
    __syncthreads();
    if (i < 7){
      #pragma unroll
      for (int ntl = 0; ntl < 2; ++ntl)
        #pragma unroll
        for (int kt = 0; kt < 2; ++kt)
          bn[ntl][kt] = wfrag(W, (i+1)*2+kt, w*2+ntl, g, ln);
    }
    bf16x8 a[2][2];
    #pragma unroll
    for (int rt = 0; rt < 2; ++rt){
      int arow = rt*16 + ln;
      #pragma unroll
      for (int kt = 0; kt < 2; ++kt)
        a[rt][kt] = *reinterpret_cast<const bf16x8*>(Xc + arow*128 + ((kt*64 + g*16) ^ ((arow&7)<<4)));
    }
    #pragma unroll
    for (int ntl = 0; ntl < 2; ++ntl)
      #pragma unroll
      for (int kt = 0; kt < 2; ++kt)
        #pragma unroll
        for (int rt = 0; rt < 2; ++rt)
          acc[rt][ntl] = __builtin_amdgcn_mfma_f32_16x16x32_bf16(a[rt][kt], bc[ntl][kt], acc[rt][ntl], 0, 0, 0);
    if (i < 7){
      #pragma unroll
      for (int ntl = 0; ntl < 2; ++ntl)
        #pragma unroll
        for (int kt = 0; kt < 2; ++kt)
          bc[ntl][kt] = bn[ntl][kt];
    }
  }

  char* Xb = reinterpret_cast<char*>(Xs[0]);
  __syncthreads();
  if (which < 2){
    // repack acc -> swizzled 32x64 LDS tile -> fragment order -> coalesced 1KB stores
    const float sc = (which==0) ? QSCALE : 1.0f;
    #pragma unroll
    for (int rt = 0; rt < 2; ++rt)
      #pragma unroll
      for (int ntl = 0; ntl < 2; ++ntl)
        #pragma unroll
        for (int r = 0; r < 4; ++r){
          int row = rt*16 + g*4 + r, col = (w*2+ntl)*16 + ln;
          *reinterpret_cast<unsigned short*>(Xb + row*128 + ((col*2) ^ ((row&7)<<4))) =
              f2bf((acc[rt][ntl][r] + bcol[ntl]) * sc);
        }
    __syncthreads();
    unsigned short* base = (which==0)
        ? wsu + WS_QF + (unsigned)(((rowbase>>4) + w)*2)*512u
        : wsu + WS_KF + (unsigned)(rowbase>>11)*131072u + (unsigned)((((rowbase&2047)>>4) + w)*2)*512u;
    const int arow = w*16 + ln;
    #pragma unroll
    for (int kt = 0; kt < 2; ++kt){
      bf16x8 f = *reinterpret_cast<const bf16x8*>(Xb + arow*128 + ((kt*64 + g*16) ^ ((arow&7)<<4)));
      *reinterpret_cast<bf16x8*>(base + kt*512 + l*8) = f;
    }
  } else {
    // V: transposed 64x32 LDS tile (swizzled) -> V^T fragments -> coalesced stores
    #pragma unroll
    for (int rt = 0; rt < 2; ++rt)
      #pragma unroll
      for (int ntl = 0; ntl < 2; ++ntl)
        #pragma unroll
        for (int r = 0; r < 4; ++r){
          int kv = rt*16 + g*4 + r, d = (w*2+ntl)*16 + ln;
          *reinterpret_cast<unsigned short*>(Xb + d*64 + ((kv*2) ^ ((d&3)<<4))) =
              f2bf(acc[rt][ntl][r] + bcol[ntl]);
        }
    __syncthreads();
    unsigned short* vfb = wsu + WS_VF + (unsigned)(rowbase>>11)*131072u;
    const int kv32 = (rowbase & 2047) >> 5;
    #pragma unroll
    for (int dtl = 0; dtl < 2; ++dtl){
      int dt = w*2 + dtl;
      int rd = dt*16 + ln;
      bf16x8 f = *reinterpret_cast<const bf16x8*>(Xb + rd*64 + ((g*16) ^ ((rd&3)<<4)));
      *reinterpret_cast<bf16x8*>(vfb + (unsigned)((kv32*4 + dt)*64 + l)*8u) = f;
    }
  }
}

// ---------------- K2: split-KV flash attention + fused output projection ----
// R12 structure (best: 32.82) + s_setprio around MFMA clusters (T5; waves are
// independent through the KV loop -> the attn-positive case, m191).
#define PSTR 72

__global__ __launch_bounds__(512) void k_attn(const unsigned short* __restrict__ wsu,
    const float* __restrict__ bo, float* __restrict__ out){
  __shared__ __attribute__((aligned(16))) unsigned char smem[42496];

  const int t = threadIdx.x;
  const int w = t >> 6, l = t & 63, g = l >> 4, ln = l & 15;
  // XCD-aware mapping: xcd = bid%8 ; batch = xcd>>1 ; tile = (bid&1)*32 + bid>>3
  const int bid = blockIdx.x;
  const int batch = (bid & 7) >> 1;
  const int tile  = ((bid & 1) << 5) | (bid >> 3);
  const int qbase = batch*2048 + tile*32;

  const unsigned short* qf  = wsu + WS_QF;
  const unsigned short* kfb = wsu + WS_KF + (unsigned)batch*131072u;
  const unsigned short* vfb = wsu + WS_VF + (unsigned)batch*131072u;
  const unsigned short* wof = wsu + WS_WOF;

  unsigned short* Pw  = (unsigned short*)(smem + w*4608);
  float*          pls = (float*)(smem + 36864);
  unsigned short* ob  = (unsigned short*)(smem + 37888);

  const int q16 = qbase >> 4;
  bf16x8 qa[2][2];
  #pragma unroll
  for (int rt = 0; rt < 2; ++rt)
    #pragma unroll
    for (int kt = 0; kt < 2; ++kt)
      qa[rt][kt] = *reinterpret_cast<const bf16x8*>(qf + (unsigned)(((q16+rt)*2 + kt)*64 + l)*8u);

  f32x4 o[4][2];
  #pragma unroll
  for (int dt = 0; dt < 4; ++dt)
    #pragma unroll
    for (int rt = 0; rt < 2; ++rt) o[dt][rt] = (f32x4){0.f,0.f,0.f,0.f};
  float ls[2] = {0.f, 0.f};

  const int kv0 = w * 256;

  #pragma unroll
  for (int it = 0; it < 4; ++it){
    const int kvb = kv0 + it*64;
    const int kv16 = kvb >> 4, kv32 = kvb >> 5;
    bf16x8 ka[4][2];
    #pragma unroll
    for (int ct = 0; ct < 4; ++ct)
      #pragma unroll
      for (int kt = 0; kt < 2; ++kt)
        ka[ct][kt] = *reinterpret_cast<const bf16x8*>(kfb + (unsigned)(((kv16+ct)*2 + kt)*64 + l)*8u);
    f32x4 st[4][2];
    __builtin_amdgcn_s_setprio(1);
    #pragma unroll
    for (int ct = 0; ct < 4; ++ct)
      #pragma unroll
      for (int rt = 0; rt < 2; ++rt){
        st[ct][rt] = (f32x4){0.f,0.f,0.f,0.f};
        #pragma unroll
        for (int kt = 0; kt < 2; ++kt)
          st[ct][rt] = __builtin_amdgcn_mfma_f32_16x16x32_bf16(ka[ct][kt], qa[rt][kt], st[ct][rt], 0,0,0);
      }
    __builtin_amdgcn_s_setprio(0);
    bf16x8 vb[4][2];
    #pragma unroll
    for (int dt = 0; dt < 4; ++dt)
      #pragma unroll
      for (int kvt = 0; kvt < 2; ++kvt)
        vb[dt][kvt] = *reinterpret_cast<const bf16x8*>(vfb + (unsigned)(((kv32+kvt)*4 + dt)*64 + l)*8u);

    #pragma unroll
    for (int rt = 0; rt < 2; ++rt){
      float p[4][4];
      float rs = 0.f;
      #pragma unroll
      for (int ct = 0; ct < 4; ++ct)
        #pragma unroll
        for (int r = 0; r < 4; ++r){
          p[ct][r] = exp2f(st[ct][rt][r]);
          rs += p[ct][r];
        }
      rs += __shfl_xor(rs, 16, 64);
      rs += __shfl_xor(rs, 32, 64);
      ls[rt] += rs;
      unsigned short* pr = Pw + (rt*16 + ln)*PSTR;
      #pragma unroll
      for (int ct = 0; ct < 4; ++ct){
        *reinterpret_cast<u32*>(pr + ct*16 + g*4)     = pk2(p[ct][0], p[ct][1]);
        *reinterpret_cast<u32*>(pr + ct*16 + g*4 + 2) = pk2(p[ct][2], p[ct][3]);
      }
    }
    bf16x8 pb[2][2];
    #pragma unroll
    for (int rt = 0; rt < 2; ++rt)
      #pragma unroll
      for (int kvt = 0; kvt < 2; ++kvt)
        pb[rt][kvt] = *reinterpret_cast<const bf16x8*>(Pw + (rt*16 + ln)*PSTR + kvt*32 + g*8);
    __builtin_amdgcn_s_setprio(1);
    #pragma unroll
    for (int dt = 0; dt < 4; ++dt)
      #pragma unroll
      for (int rt = 0; rt < 2; ++rt)
        #pragma unroll
        for (int kvt = 0; kvt < 2; ++kvt)
          o[dt][rt] = __builtin_amdgcn_mfma_f32_16x16x32_bf16(vb[dt][kvt], pb[rt][kvt], o[dt][rt], 0,0,0);
    __builtin_amdgcn_s_setprio(0);
  }

  if (l < 16){ pls[w*32 + ln] = ls[0]; pls[w*32 + 16 + ln] = ls[1]; }
  unsigned short* pow_ = (unsigned short*)(smem + w*4608);
  #pragma unroll
  for (int dt = 0; dt < 4; ++dt)
    #pragma unroll
    for (int rt = 0; rt < 2; ++rt){
      u32* dst = reinterpret_cast<u32*>(pow_ + (rt*16 + ln)*68 + dt*16 + g*4);
      dst[0] = pk2(o[dt][rt][0], o[dt][rt][1]);
      dst[1] = pk2(o[dt][rt][2], o[dt][rt][3]);
    }
  __syncthreads();

  #pragma unroll
  for (int i = 0; i < 4; ++i){
    int idx = t + i*512;
    int row = idx >> 6, d = idx & 63;
    float den = 0.f, num = 0.f;
    #pragma unroll
    for (int w2 = 0; w2 < 8; ++w2){
      den += pls[w2*32 + row];
      num += bf2f(*((const unsigned short*)(smem + w2*4608) + row*68 + d));
    }
    ob[row*PSTR + d] = f2bf(num / den);
  }
  __syncthreads();

  const int colbase = w*64;
  bf16x8 ao[2][2];
  #pragma unroll
  for (int rt = 0; rt < 2; ++rt)
    #pragma unroll
    for (int kt = 0; kt < 2; ++kt)
      ao[rt][kt] = *reinterpret_cast<const bf16x8*>(ob + (rt*16 + ln)*PSTR + kt*32 + g*8);
  f32x4 oc[2][4];
  #pragma unroll
  for (int rt = 0; rt < 2; ++rt)
    #pragma unroll
    for (int nt = 0; nt < 4; ++nt) oc[rt][nt] = (f32x4){0.f,0.f,0.f,0.f};
  #pragma unroll
  for (int nt = 0; nt < 4; ++nt){
    #pragma unroll
    for (int kt = 0; kt < 2; ++kt){
      bf16x8 b = *reinterpret_cast<const bf16x8*>(wof + (unsigned)(((w*4+nt)*2 + kt)*64 + l)*8u);
      #pragma unroll
      for (int rt = 0; rt < 2; ++rt)
        oc[rt][nt] = __builtin_amdgcn_mfma_f32_16x16x32_bf16(ao[rt][kt], b, oc[rt][nt], 0,0,0);
    }
  }
  #pragma unroll
  for (int nt = 0; nt < 4; ++nt){
    float bc = bo[colbase + nt*16 + ln];
    #pragma unroll
    for (int rt = 0; rt < 2; ++rt){
      #pragma unroll
      for (int r = 0; r < 4; ++r){
        int row = qbase + rt*16 + g*4 + r;
        __builtin_nontemporal_store(oc[rt][nt][r] + bc, &out[row*512 + colbase + nt*16 + ln]);
      }
    }
  }
}

extern "C" void kernel_launch(void* const* d_in, const int* in_sizes, int n_in,
                              void* d_out, int out_size, void* d_ws, size_t ws_size,
                              hipStream_t stream){
  const float* q  = (const float*)d_in[0];
  const float* k  = (const float*)d_in[1];
  const float* v  = (const float*)d_in[2];
  const float* Wq = (const float*)d_in[3];
  const float* bq = (const float*)d_in[4];
  const float* Wk = (const float*)d_in[5];
  const float* bk = (const float*)d_in[6];
  const float* Wv = (const float*)d_in[7];
  const float* bv = (const float*)d_in[8];
  const float* Wo = (const float*)d_in[9];
  const float* bo = (const float*)d_in[10];
  float* out = (float*)d_out;
  unsigned short* wsu = (unsigned short*)d_ws;

  k_proj<<<dim3(256, 4), dim3(128), 0, stream>>>(q, k, v, bq, bk, bv, Wq, Wk, Wv, Wo, wsu);
  k_attn<<<dim3(256), dim3(512), 0, stream>>>(wsu, bo, out);
}